// Round 2
// baseline (213.200 us; speedup 1.0000x reference)
//
#include <hip/hip_runtime.h>

// FlowNetC correlation, B=8 C=256 H=64 W=128, 9x9 displacement grid.
// out[b,(i+4)*9+(j+4),h,w] = (1/256) * sum_c in1[b,c,h,w]*in2[b,c,h+i,w+j]
// (in2 zero-padded by 4 in h,w).
//
// 256 blocks (b x 2-row h-tile) x 576 threads (9 waves, wave = dy).
// Lane = (q: 8 w-px, hp: h row, cs: channel half). acc[8px][9dx]/lane.
// Phased: KC=4 channel-units per barrier, double-buffered LDS (87 KB).
// Staging front-loaded at phase top via global_load_lds (parity-deinterleaved
// layout, conflict-free b128 reads); v1 prefetched one full phase ahead into
// v1buf[4][8]; counted vmcnt(8) keeps v1 prefetch in flight across barriers.
// NOTE: no 2nd __launch_bounds__ arg — (576,3) made the compiler cap VGPR at
// 84 -> inner-loop scratch spill (R1: 227us, VALUBusy 23%).

#define AS1 __attribute__((address_space(1)))
#define AS3 __attribute__((address_space(3)))

namespace {

constexpr int Cc = 256, Hh = 64, Ww = 128;
constexpr int HW = Hh * Ww;            // 8192
constexpr int ND = 81;
constexpr int RSTRIDE = 136;           // 4 zero | 128 data (deinterleaved) | 4 zero
constexpr int CHSTR = 10 * RSTRIDE;    // 1360 floats per (unit, cs-half)
constexpr int UNITSTR = 2 * CHSTR;     // 2720 floats per channel-unit
constexpr int KC = 4;                  // channel-units per phase
constexpr int BUFSTR = KC * UNITSTR;   // 10880
constexpr int NPH = 128 / KC;          // 32 phases

__device__ __forceinline__ void async4(const float* g, float* l) {
  __builtin_amdgcn_global_load_lds((const AS1 unsigned int*)(g),
                                   (AS3 unsigned int*)(l), 4, 0, 0);
}

__global__ __launch_bounds__(576) void corr_kernel(
    const float* __restrict__ in1, const float* __restrict__ in2,
    float* __restrict__ out) {
  __shared__ __align__(16) float lds[2 * BUFSTR];  // 87040 B

  const int tid = threadIdx.x;
  const int dyw = tid >> 6;          // wave id = dy 0..8
  const int lane = tid & 63;
  const int q = lane & 15;           // 8 w-pixels: w = 8q..8q+7
  const int hp = (lane >> 4) & 1;    // h row within tile
  const int cs = lane >> 5;          // channel half

  const int bid = blockIdx.x;
  const int b = bid >> 5;
  const int h0 = (bid & 31) << 1;

  // zero the pad slots (0..3, 132..135 of each row) once; never overwritten
  for (int s = tid; s < 1280; s += 576) {
    int sl = s & 7; int t = s >> 3;
    int row = t % 10; t /= 10;
    int csx = t & 1; t >>= 1;
    int unit = t & 3; int buf = t >> 2;
    lds[buf * BUFSTR + unit * UNITSTR + csx * CHSTR + row * RSTRIDE +
        (sl < 4 ? sl : 128 + sl)] = 0.0f;
  }
  __syncthreads();

  // staging: 40 wave-loads per channel-unit (2 cs x 10 rows x 2 row-halves),
  // 5 per wave (wave 8 duplicates 5 of wave 0's benignly).
  // Deinterleaved source x so the LDS layout is conflict-free for b128 reads:
  const int sx0 = 8 * (lane >> 2) + (lane & 3) + 4;  // x%8 in 4..7 -> phys 4+i
  const int sx1 = sx0 - 4;                           // x%8 in 0..3 -> phys 68+i
  const size_t in2_b = (size_t)b * Cc * HW;

  int ldsoff[5]; int goff[5]; bool gval[5];
#pragma unroll
  for (int k = 0; k < 5; ++k) {
    int u = dyw * 5 + k; if (u >= 40) u -= 40;
    int cs_u = u / 20; int rem = u - cs_u * 20;
    int rr = rem >> 1; int half = rem & 1;
    int grow = h0 - 4 + rr;
    ldsoff[k] = cs_u * CHSTR + rr * RSTRIDE + 4 + 64 * half;
    goff[k] = cs_u * 128 * HW + grow * Ww + (half ? sx1 : sx0);
    gval[k] = (unsigned)grow < (unsigned)Hh;
  }

  auto stage = [&](int j) {  // global channel-unit j in 0..127
    const int lb = ((j >> 2) & 1) * BUFSTR + (j & 3) * UNITSTR;
    const float* in2j = in2 + in2_b + (size_t)j * HW;
#pragma unroll
    for (int k = 0; k < 5; ++k) {
      float* ldst = &lds[lb + ldsoff[k]];
      if (gval[k]) async4(in2j + goff[k], ldst);
      else         ldst[lane] = 0.0f;
    }
  };

  const int rb = cs * CHSTR + (dyw + hp) * RSTRIDE + 4 * q;
  const float* in1p =
      in1 + ((size_t)(b * Cc + cs * 128) * Hh + (h0 + hp)) * Ww + 8 * q;

  float acc[8][9];
#pragma unroll
  for (int px = 0; px < 8; ++px)
#pragma unroll
    for (int dx = 0; dx < 9; ++dx) acc[px][dx] = 0.0f;

  // v1 prefetch buffer: phase-0 channels 0..3
  float v1buf[4][8];
#pragma unroll
  for (int c = 0; c < 4; ++c) {
    const float* pp = in1p + (size_t)c * HW;
    float4 a = *(const float4*)pp; float4 d = *(const float4*)(pp + 4);
    v1buf[c][0] = a.x; v1buf[c][1] = a.y; v1buf[c][2] = a.z; v1buf[c][3] = a.w;
    v1buf[c][4] = d.x; v1buf[c][5] = d.y; v1buf[c][6] = d.z; v1buf[c][7] = d.w;
  }
  stage(0); stage(1); stage(2); stage(3);
  asm volatile("s_waitcnt vmcnt(0) lgkmcnt(0)" ::: "memory");
  __builtin_amdgcn_s_barrier();
  __builtin_amdgcn_sched_barrier(0);

  for (int p = 0; p < NPH; ++p) {
    const int bb = (p & 1) * BUFSTR;
    const bool morep = (p + 1 < NPH);
    if (morep) {  // front-load all next-phase staging (20 loads)
      stage((p + 1) * 4 + 0); stage((p + 1) * 4 + 1);
      stage((p + 1) * 4 + 2); stage((p + 1) * 4 + 3);
      __builtin_amdgcn_sched_barrier(0);
    }
#pragma unroll
    for (int c = 0; c < 4; ++c) {
      const int base = bb + c * UNITSTR + rb;
      const float4 W0 = *(const float4*)&lds[base];       // window t0..3
      const float4 Wa = *(const float4*)&lds[base + 4];   // t8..11
      const float4 W2 = *(const float4*)&lds[base + 68];  // t4..7
      const float4 Wb = *(const float4*)&lds[base + 72];  // t12..15
      const float t[16] = {W0.x, W0.y, W0.z, W0.w, W2.x, W2.y, W2.z, W2.w,
                           Wa.x, Wa.y, Wa.z, Wa.w, Wb.x, Wb.y, Wb.z, Wb.w};
#pragma unroll
      for (int dx = 0; dx < 9; ++dx)
#pragma unroll
        for (int px = 0; px < 8; ++px)
          acc[px][dx] = fmaf(v1buf[c][px], t[px + dx], acc[px][dx]);
      if (c >= 2 && morep) {  // late reload: next-phase v1, used next phase
#pragma unroll
        for (int r = 0; r < 2; ++r) {
          const int cc = (c - 2) * 2 + r;
          const float* pp = in1p + (size_t)((p + 1) * 4 + cc) * HW;
          float4 a = *(const float4*)pp; float4 d = *(const float4*)(pp + 4);
          v1buf[cc][0] = a.x; v1buf[cc][1] = a.y;
          v1buf[cc][2] = a.z; v1buf[cc][3] = a.w;
          v1buf[cc][4] = d.x; v1buf[cc][5] = d.y;
          v1buf[cc][6] = d.z; v1buf[cc][7] = d.w;
        }
      }
    }
    if (morep) {
      __builtin_amdgcn_sched_barrier(0);
      // drain staging (older), keep the 8 v1 prefetch loads in flight
      asm volatile("s_waitcnt vmcnt(8) lgkmcnt(0)" ::: "memory");
      __builtin_amdgcn_s_barrier();
      __builtin_amdgcn_sched_barrier(0);
    }
  }

  // reduce channel halves
#pragma unroll
  for (int px = 0; px < 8; ++px)
#pragma unroll
    for (int dx = 0; dx < 9; ++dx)
      acc[px][dx] += __shfl_xor(acc[px][dx], 32, 64);

  const float s = 1.0f / 256.0f;
  float* outp =
      out + (((size_t)b * ND + (size_t)dyw * 9) * Hh + (h0 + hp)) * Ww + 8 * q;
  if (cs == 0) {
#pragma unroll
    for (int dx = 0; dx < 5; ++dx) {
      float4 lo = make_float4(acc[0][dx] * s, acc[1][dx] * s, acc[2][dx] * s,
                              acc[3][dx] * s);
      float4 hi = make_float4(acc[4][dx] * s, acc[5][dx] * s, acc[6][dx] * s,
                              acc[7][dx] * s);
      *(float4*)(outp + (size_t)dx * HW) = lo;
      *(float4*)(outp + (size_t)dx * HW + 4) = hi;
    }
  } else {
#pragma unroll
    for (int dx = 4; dx < 9; ++dx) {  // dx=4 written by both halves, same value
      float4 lo = make_float4(acc[0][dx] * s, acc[1][dx] * s, acc[2][dx] * s,
                              acc[3][dx] * s);
      float4 hi = make_float4(acc[4][dx] * s, acc[5][dx] * s, acc[6][dx] * s,
                              acc[7][dx] * s);
      *(float4*)(outp + (size_t)dx * HW) = lo;
      *(float4*)(outp + (size_t)dx * HW + 4) = hi;
    }
  }
}

}  // namespace

extern "C" void kernel_launch(void* const* d_in, const int* in_sizes, int n_in,
                              void* d_out, int out_size, void* d_ws,
                              size_t ws_size, hipStream_t stream) {
  (void)in_sizes; (void)n_in; (void)out_size; (void)d_ws; (void)ws_size;
  const float* in1 = (const float*)d_in[0];
  const float* in2 = (const float*)d_in[1];
  float* outp = (float*)d_out;
  corr_kernel<<<256, 576, 0, stream>>>(in1, in2, outp);
}